// Round 1
// baseline (102.022 us; speedup 1.0000x reference)
//
#include <hip/hip_runtime.h>

// HankelCovLayer: Ry[b,i,j] = (1/L) * sum_l v[i+l] * conj(v[j+l]),
// v[k] = complex(in[b,0,k+2], in[b,1,k+2]), k in [0,252), L=245, i,j in [0,8).
// Strategy: compute only row 0 via full dots S[d] = sum_l v[l]*conj(v[l+d]),
// reconstruct the rest via the Hankel recurrence + Hermitian symmetry.

#define NBATCH   32768
#define SDIM     256
#define LDIM     245
#define BPB      16          // batches per block
#define BSTRIDE  548         // dwords per batch LDS region (274 complex)

// XOR-swizzle on 16B-block index: breaks the 32-dword (16-complex) lane stride
// of the window reads into <=2-way bank aliasing (free per m136).
__device__ __forceinline__ int swz_blk(int blk) {
  return blk ^ ((blk >> 4) & 7);
}

// complex load (entry c) through the swizzled layout; b64, never straddles a block
__device__ __forceinline__ float2 ldc(const float* base, int c) {
  const int dw = 2 * c;
  const float* p = base + 4 * swz_blk(dw >> 2) + (dw & 3);
  return make_float2(p[0], p[1]);
}

// x += dpp_shifted(x); after ctrl = row_shr 1,2,4,8 the 16-lane row sum is in lane 15.
#define DPP_ADD(x, ctrl)                                                            \
  {                                                                                 \
    int _dt = __builtin_amdgcn_update_dpp(0, __builtin_bit_cast(int, (x)),          \
                                          (ctrl), 0xF, 0xF, true);                  \
    (x) += __builtin_bit_cast(float, _dt);                                          \
  }

extern "C" __global__ __launch_bounds__(256, 4)
void HankelCovLayer_23167053595379_kernel(const float* __restrict__ in,
                                          float* __restrict__ out) {
  __shared__ __align__(16) float lds[BPB * BSTRIDE];   // 35072 B
  __shared__ __align__(16) float sbuf[BPB * 16];       // S[d] per batch, 1024 B

  const int t = threadIdx.x;
  const long long blockBase = (long long)blockIdx.x * BPB * (2 * SDIM);

  // ---------------- stage 16 batches -> LDS (interleaved complex, swizzled) ----
  {
    const int u  = t & 63;
    const int wv = t >> 6;
#pragma unroll
    for (int k = 0; k < 4; ++k) {
      const int bl = k * 4 + wv;
      const float* src = in + blockBase + (long long)bl * (2 * SDIM);
      const float4 re = *(const float4*)(src + 4 * u);
      const float4 im = *(const float4*)(src + SDIM + 4 * u);
      float* bb = lds + bl * BSTRIDE;
      const float4 p0 = make_float4(re.x, im.x, re.y, im.y);  // complex 4u,4u+1
      const float4 p1 = make_float4(re.z, im.z, re.w, im.w);  // complex 4u+2,4u+3
      *(float4*)(bb + 4 * swz_blk(2 * u))     = p0;
      *(float4*)(bb + 4 * swz_blk(2 * u + 1)) = p1;
    }
    // zero-pad complex entries 256..273 (blocks 128..136; identity under swizzle)
    for (int z = t; z < BPB * 9; z += 256) {
      const int bl = z / 9, blk = 128 + z % 9;
      *(float4*)(lds + bl * BSTRIDE + 4 * blk) = make_float4(0.f, 0.f, 0.f, 0.f);
    }
  }
  __syncthreads();

  // ---------------- per-16-lane-group: one batch ------------------------------
  const int lane = t & 63;
  const int wv   = t >> 6;
  const int g    = lane >> 4;
  const int h    = lane & 15;
  const int bl   = wv * 4 + g;
  const float* base = lds + bl * BSTRIDE;

  // register window: v[16h .. 16h+23]  (logical blocks 8h+1 .. 8h+12)
  float win[48];
  {
    const int blk0 = 8 * h + 1;
#pragma unroll
    for (int r = 0; r < 12; ++r)
      *(float4*)(win + 4 * r) = *(const float4*)(base + 4 * swz_blk(blk0 + r));
  }

  float Sr[8], Si[8];
#pragma unroll
  for (int d = 0; d < 8; ++d) { Sr[d] = 0.f; Si[d] = 0.f; }

  const int l0 = 16 * h;
#pragma unroll
  for (int m = 0; m < 16; ++m) {
    const bool ok = (l0 + m) < LDIM;            // mask tail l >= 245 (lane 15)
    const float ar = ok ? win[2 * m]     : 0.f;
    const float ai = ok ? win[2 * m + 1] : 0.f;
#pragma unroll
    for (int d = 0; d < 8; ++d) {
      const float br = win[2 * (m + d)];
      const float bi = win[2 * (m + d) + 1];
      Sr[d] = fmaf(ar, br, fmaf(ai, bi, Sr[d]));     // Re(a * conj(b))
      Si[d] = fmaf(ai, br, fmaf(-ar, bi, Si[d]));    // Im(a * conj(b))
    }
  }

  // reduce each S[d] across the 16-lane row on the VALU (DPP); sum lands in lane 15
#pragma unroll
  for (int d = 0; d < 8; ++d) {
    DPP_ADD(Sr[d], 0x111); DPP_ADD(Sr[d], 0x112);
    DPP_ADD(Sr[d], 0x114); DPP_ADD(Sr[d], 0x118);
    if (d) {
      DPP_ADD(Si[d], 0x111); DPP_ADD(Si[d], 0x112);
      DPP_ADD(Si[d], 0x114); DPP_ADD(Si[d], 0x118);
    }
  }

  if (h == 15) {                                   // park S in LDS (static regs)
    float4* sp = (float4*)(sbuf + bl * 16);
    sp[0] = make_float4(Sr[0], 0.f,   Sr[1], Si[1]);
    sp[1] = make_float4(Sr[2], Si[2], Sr[3], Si[3]);
    sp[2] = make_float4(Sr[4], Si[4], Sr[5], Si[5]);
    sp[3] = make_float4(Sr[6], Si[6], Sr[7], Si[7]);
  }
  __syncthreads();

  // ---------------- epilogue: recurrence corrections + coalesced store --------
  const float invL = 1.0f / (float)LDIM;
  float* op = out + ((long long)blockIdx.x * BPB + bl) * 128;
  const float* sp = sbuf + bl * 16;

#pragma unroll
  for (int q = 0; q < 4; ++q) {
    const int i  = 2 * q + (h >> 3);
    const int j  = h & 7;
    const int d  = (i > j) ? (i - j) : (j - i);
    const int mn = (i < j) ? i : j;

    float xr = sp[2 * d];
    float xi = sp[2 * d + 1];

    for (int k = 0; k < mn; ++k) {
      // + v[245+k]*conj(v[245+k+d]) - v[k]*conj(v[k+d]);  entry(c) = v[c-2]
      const float2 a1 = ldc(base, 247 + k);
      const float2 b1 = ldc(base, 247 + k + d);
      const float2 a0 = ldc(base, 2 + k);
      const float2 b0 = ldc(base, 2 + k + d);
      xr += (a1.x * b1.x + a1.y * b1.y) - (a0.x * b0.x + a0.y * b0.y);
      xi += (a1.y * b1.x - a1.x * b1.y) - (a0.y * b0.x - a0.x * b0.y);
    }
    if (i > j) xi = -xi;                          // Hermitian: R[i][j] = conj(R[j][i])

    const int e = h + 16 * q;                     // e = i*8 + j; coalesced per row
    *(float2*)(op + 2 * e) = make_float2(xr * invL, xi * invL);
  }
}

extern "C" void kernel_launch(void* const* d_in, const int* in_sizes, int n_in,
                              void* d_out, int out_size, void* d_ws, size_t ws_size,
                              hipStream_t stream) {
  const float* in = (const float*)d_in[0];
  float* out = (float*)d_out;
  hipLaunchKernelGGL(HankelCovLayer_23167053595379_kernel,
                     dim3(NBATCH / BPB), dim3(256), 0, stream, in, out);
}

// Round 2
// 99.133 us; speedup vs baseline: 1.0291x; 1.0291x over previous
//
#include <hip/hip_runtime.h>

// HankelCovLayer: Ry[b,i,j] = (1/L) * sum_l v[i+l] * conj(v[j+l]),
// v[k] = complex(in[b,0,k+2], in[b,1,k+2]), k in [0,252), L=245, i,j in [0,8).
// Row 0 via full dots S[d]; rest via Hankel recurrence prefix table + Hermitian.
// BARRIER-FREE: each wave stages/computes its own 4 batches (wave-private LDS
// dataflow), so no __syncthreads is needed — waves pipeline independently.

#define NBATCH   32768
#define SDIM     256
#define LDIM     245
#define BPB      16          // batches per block (4 per wave)
#define BSTRIDE  548         // dwords per batch LDS region (137 16B-blocks)

// XOR-swizzle on 16B-block index: breaks the 8-block (16-complex) lane stride
// of the window reads into 2-way bank aliasing (free per m136).
__device__ __forceinline__ int swz_blk(int blk) {
  return blk ^ ((blk >> 4) & 7);
}

// complex load (entry c) through the swizzled layout; 8B-aligned, in-block
__device__ __forceinline__ float2 ldc(const float* base, int c) {
  const float* p = base + 4 * swz_blk(c >> 1) + 2 * (c & 1);
  return make_float2(p[0], p[1]);
}

// x += dpp_shifted(x); ctrl = row_shr 1,2,4,8 -> 16-lane row sum lands in lane 15
#define DPP_ADD(x, ctrl)                                                            \
  {                                                                                 \
    int _dt = __builtin_amdgcn_update_dpp(0, __builtin_bit_cast(int, (x)),          \
                                          (ctrl), 0xF, 0xF, true);                  \
    (x) += __builtin_bit_cast(float, _dt);                                          \
  }

extern "C" __global__ __launch_bounds__(256, 4)
void HankelCovLayer_23167053595379_kernel(const float* __restrict__ in,
                                          float* __restrict__ out) {
  __shared__ __align__(16) float lds[BPB * BSTRIDE];   // 35072 B
  __shared__ __align__(16) float atab[BPB * 72];       // A_d(n) table, 4608 B

  const int t    = threadIdx.x;
  const int lane = t & 63;
  const int wv   = t >> 6;
  const long long blockBase = (long long)blockIdx.x * BPB * (2 * SDIM);

  // ------- stage: wave wv loads its own 4 batches (interleaved cplx, swizzled)
#pragma unroll
  for (int k = 0; k < 4; ++k) {
    const int bl = wv * 4 + k;
    const float* src = in + blockBase + (long long)bl * (2 * SDIM);
    const float4 re = *(const float4*)(src + 4 * lane);
    const float4 im = *(const float4*)(src + SDIM + 4 * lane);
    float* bb = lds + bl * BSTRIDE;
    *(float4*)(bb + 4 * swz_blk(2 * lane))     = make_float4(re.x, im.x, re.y, im.y);
    *(float4*)(bb + 4 * swz_blk(2 * lane + 1)) = make_float4(re.z, im.z, re.w, im.w);
  }
  // zero-pad blocks 128..132 (complex 256..265; window b-side tail) per own batch
  if (lane < 20) {
    const int bl  = wv * 4 + lane / 5;
    const int blk = 128 + lane % 5;          // identity under swizzle
    *(float4*)(lds + bl * BSTRIDE + 4 * blk) = make_float4(0.f, 0.f, 0.f, 0.f);
  }
  // NO __syncthreads: all LDS producer/consumer pairs are within this wave.

  // ------- per-16-lane-group: one batch --------------------------------------
  const int g  = lane >> 4;
  const int h  = lane & 15;
  const int bl = wv * 4 + g;
  const float* base = lds + bl * BSTRIDE;

  // register window: v[16h .. 16h+23]  (logical blocks 8h+1 .. 8h+12)
  float win[48];
  {
    const int blk0 = 8 * h + 1;
#pragma unroll
    for (int r = 0; r < 12; ++r)
      *(float4*)(win + 4 * r) = *(const float4*)(base + 4 * swz_blk(blk0 + r));
  }

  float Sr[8], Si[8];
#pragma unroll
  for (int d = 0; d < 8; ++d) { Sr[d] = 0.f; Si[d] = 0.f; }

  const int l0 = 16 * h;
#pragma unroll
  for (int m = 0; m < 16; ++m) {
    const bool ok = (l0 + m) < LDIM;            // mask tail l >= 245 (lane 15)
    const float ar = ok ? win[2 * m]     : 0.f;
    const float ai = ok ? win[2 * m + 1] : 0.f;
#pragma unroll
    for (int d = 0; d < 8; ++d) {
      const float br = win[2 * (m + d)];
      const float bi = win[2 * (m + d) + 1];
      Sr[d] = fmaf(ar, br, fmaf(ai, bi, Sr[d]));     // Re(a * conj(b))
      Si[d] = fmaf(ai, br, fmaf(-ar, bi, Si[d]));    // Im(a * conj(b))
    }
  }

  // reduce S[d] across the 16-lane row on the VALU (DPP); sums land in lane 15
#pragma unroll
  for (int d = 0; d < 8; ++d) {
    DPP_ADD(Sr[d], 0x111); DPP_ADD(Sr[d], 0x112);
    DPP_ADD(Sr[d], 0x114); DPP_ADD(Sr[d], 0x118);
    if (d) {
      DPP_ADD(Si[d], 0x111); DPP_ADD(Si[d], 0x112);
      DPP_ADD(Si[d], 0x114); DPP_ADD(Si[d], 0x118);
    }
  }

  // ------- prefix table A_d(n) = S[d] + sum_{k<n} delta(d,k), n in [0, 7-d] --
  // triangular layout at offset off(d) = d*(17-d)/2 complex; 36 complex/batch
  float* ap = atab + bl * 72;
  if (h == 15) {                                   // seed n=0 entries with S[d]
#pragma unroll
    for (int d = 0; d < 8; ++d) {
      const int off = (d * (17 - d)) >> 1;         // compile-time after unroll
      *(float2*)(ap + 2 * off) = make_float2(Sr[d], d ? Si[d] : 0.f);
    }
  }
  {
    const int d    = h;                            // lanes 0..7 build row d
    const int offd = (h * (17 - h)) >> 1;
    float2 acc = make_float2(0.f, 0.f);
    if (h < 8) acc = *(const float2*)(ap + 2 * offd);   // same-wave LDS RAW
#pragma unroll
    for (int k = 0; k < 7; ++k) {
      if (h + k < 7) {                             // lane d does n = 1..7-d
        const float2 a1 = ldc(base, 247 + k);
        const float2 b1 = ldc(base, 247 + k + d);
        const float2 a0 = ldc(base, 2 + k);
        const float2 b0 = ldc(base, 2 + k + d);
        acc.x += (a1.x * b1.x + a1.y * b1.y) - (a0.x * b0.x + a0.y * b0.y);
        acc.y += (a1.y * b1.x - a1.x * b1.y) - (a0.y * b0.x - a0.x * b0.y);
        *(float2*)(ap + 2 * (offd + k + 1)) = acc;
      }
    }
  }

  // ------- epilogue: one b64 table read per entry + coalesced store ----------
  const float invL = 1.0f / (float)LDIM;
  float* op = out + ((long long)blockIdx.x * BPB + bl) * 128;

#pragma unroll
  for (int q = 0; q < 4; ++q) {
    const int i  = 2 * q + (h >> 3);
    const int j  = h & 7;
    const int d  = (i > j) ? (i - j) : (j - i);
    const int mn = (i < j) ? i : j;
    const int off = (d * (17 - d)) >> 1;

    const float2 r = *(const float2*)(ap + 2 * (off + mn));
    const float xi = (i > j) ? -r.y : r.y;         // Hermitian: R[i][j]=conj(R[j][i])

    const int e = h + 16 * q;                      // e = i*8 + j; coalesced per row
    *(float2*)(op + 2 * e) = make_float2(r.x * invL, xi * invL);
  }
}

extern "C" void kernel_launch(void* const* d_in, const int* in_sizes, int n_in,
                              void* d_out, int out_size, void* d_ws, size_t ws_size,
                              hipStream_t stream) {
  const float* in = (const float*)d_in[0];
  float* out = (float*)d_out;
  hipLaunchKernelGGL(HankelCovLayer_23167053595379_kernel,
                     dim3(NBATCH / BPB), dim3(256), 0, stream, in, out);
}

// Round 3
// 97.731 us; speedup vs baseline: 1.0439x; 1.0143x over previous
//
#include <hip/hip_runtime.h>

// HankelCovLayer: Ry[b,i,j] = (1/L) * sum_l v[i+l] * conj(v[j+l]),
// v[k] = complex(in[b,0,k+2], in[b,1,k+2]), k in [0,252), L=245, i,j in [0,8).
// Row 0 via full dots S[d]; rest via Hankel recurrence prefix table + Hermitian.
// Barrier-free (wave-private LDS dataflow). Dot products use v_pk_fma_f32:
//   P[d] += (ar,ai)*(br,bi)   -> Sr[d] = P.x + P.y
//   Q[d] += (ai,ar)*(br,bi)   -> Si[d] = Q.x - Q.y   (Si[0] == 0, Q[0] dropped)

#define NBATCH   32768
#define SDIM     256
#define LDIM     245
#define BPB      16          // batches per block (4 per wave)
#define BSTRIDE  548         // dwords per batch LDS region (137 16B-blocks)

typedef float v2f __attribute__((ext_vector_type(2)));

__device__ __forceinline__ v2f fma2(v2f a, v2f b, v2f c) {
  return __builtin_elementwise_fma(a, b, c);
}

// XOR-swizzle on 16B-block index: breaks the 8-block (16-complex) lane stride
// of the window reads into 2-way bank aliasing (free per m136).
__device__ __forceinline__ int swz_blk(int blk) {
  return blk ^ ((blk >> 4) & 7);
}

// complex load (entry c) through the swizzled layout; 8B-aligned, in-block
__device__ __forceinline__ float2 ldc(const float* base, int c) {
  const float* p = base + 4 * swz_blk(c >> 1) + 2 * (c & 1);
  return make_float2(p[0], p[1]);
}

// x += dpp_shifted(x); ctrl = row_shr 1,2,4,8 -> 16-lane row sum lands in lane 15
#define DPP_ADD(x, ctrl)                                                            \
  {                                                                                 \
    int _dt = __builtin_amdgcn_update_dpp(0, __builtin_bit_cast(int, (x)),          \
                                          (ctrl), 0xF, 0xF, true);                  \
    (x) += __builtin_bit_cast(float, _dt);                                          \
  }

extern "C" __global__ __launch_bounds__(256, 4)
void HankelCovLayer_23167053595379_kernel(const float* __restrict__ in,
                                          float* __restrict__ out) {
  __shared__ __align__(16) float lds[BPB * BSTRIDE];   // 35072 B
  __shared__ __align__(16) float atab[BPB * 72];       // A_d(n) table, 4608 B

  const int t    = threadIdx.x;
  const int lane = t & 63;
  const int wv   = t >> 6;
  const long long blockBase = (long long)blockIdx.x * BPB * (2 * SDIM);

  // ------- stage: wave wv loads its own 4 batches (interleaved cplx, swizzled)
#pragma unroll
  for (int k = 0; k < 4; ++k) {
    const int bl = wv * 4 + k;
    const float* src = in + blockBase + (long long)bl * (2 * SDIM);
    const float4 re = *(const float4*)(src + 4 * lane);
    const float4 im = *(const float4*)(src + SDIM + 4 * lane);
    float* bb = lds + bl * BSTRIDE;
    *(float4*)(bb + 4 * swz_blk(2 * lane))     = make_float4(re.x, im.x, re.y, im.y);
    *(float4*)(bb + 4 * swz_blk(2 * lane + 1)) = make_float4(re.z, im.z, re.w, im.w);
  }
  // zero-pad blocks 128..132 (complex 256..265; window b-side tail) per own batch
  if (lane < 20) {
    const int bl  = wv * 4 + lane / 5;
    const int blk = 128 + lane % 5;          // identity under swizzle
    *(float4*)(lds + bl * BSTRIDE + 4 * blk) = make_float4(0.f, 0.f, 0.f, 0.f);
  }
  // NO __syncthreads: all LDS producer/consumer pairs are within this wave.

  // ------- per-16-lane-group: one batch --------------------------------------
  const int g  = lane >> 4;
  const int h  = lane & 15;
  const int bl = wv * 4 + g;
  const float* base = lds + bl * BSTRIDE;

  // register window: v[16h .. 16h+23]  (logical blocks 8h+1 .. 8h+12)
  __align__(16) v2f win2[24];
  {
    const int blk0 = 8 * h + 1;
#pragma unroll
    for (int r = 0; r < 12; ++r)
      *(float4*)&win2[2 * r] = *(const float4*)(base + 4 * swz_blk(blk0 + r));
  }

  v2f P[8], Q[7];
#pragma unroll
  for (int d = 0; d < 8; ++d) P[d] = (v2f)(0.f);
#pragma unroll
  for (int d = 0; d < 7; ++d) Q[d] = (v2f)(0.f);

  const int l0 = 16 * h;
#pragma unroll
  for (int m = 0; m < 16; ++m) {
    const bool ok = (l0 + m) < LDIM;            // mask tail l >= 245 (lane 15)
    v2f va = win2[m];
    if (!ok) va = (v2f)(0.f);
    const v2f vs = va.yx;                       // (ai, ar)
    P[0] = fma2(va, win2[m], P[0]);             // d=0: b==a (mask via a)
#pragma unroll
    for (int d = 1; d < 8; ++d) {
      const v2f vb = win2[m + d];
      P[d]     = fma2(va, vb, P[d]);            // (ar*br, ai*bi)
      Q[d - 1] = fma2(vs, vb, Q[d - 1]);        // (ai*br, ar*bi)
    }
  }

  float Sr[8], Si[8];
  Sr[0] = P[0].x + P[0].y;
  Si[0] = 0.f;                                  // sum(ai*ar - ar*ai) == 0
#pragma unroll
  for (int d = 1; d < 8; ++d) {
    Sr[d] = P[d].x + P[d].y;
    Si[d] = Q[d - 1].x - Q[d - 1].y;
  }

  // reduce S[d] across the 16-lane row on the VALU (DPP); sums land in lane 15
#pragma unroll
  for (int d = 0; d < 8; ++d) {
    DPP_ADD(Sr[d], 0x111); DPP_ADD(Sr[d], 0x112);
    DPP_ADD(Sr[d], 0x114); DPP_ADD(Sr[d], 0x118);
    if (d) {
      DPP_ADD(Si[d], 0x111); DPP_ADD(Si[d], 0x112);
      DPP_ADD(Si[d], 0x114); DPP_ADD(Si[d], 0x118);
    }
  }

  // ------- prefix table A_d(n) = S[d] + sum_{k<n} delta(d,k), n in [0, 7-d] --
  // triangular layout at offset off(d) = d*(17-d)/2 complex; 36 complex/batch
  float* ap = atab + bl * 72;
  if (h == 15) {                                   // seed n=0 entries with S[d]
#pragma unroll
    for (int d = 0; d < 8; ++d) {
      const int off = (d * (17 - d)) >> 1;         // compile-time after unroll
      *(float2*)(ap + 2 * off) = make_float2(Sr[d], Si[d]);
    }
  }
  {
    const int d    = h;                            // lanes 0..7 build row d
    const int offd = (h * (17 - h)) >> 1;
    float2 acc = make_float2(0.f, 0.f);
    if (h < 8) acc = *(const float2*)(ap + 2 * offd);   // same-wave LDS RAW
#pragma unroll
    for (int k = 0; k < 7; ++k) {
      if (h + k < 7) {                             // lane d does n = 1..7-d
        const float2 a1 = ldc(base, 247 + k);
        const float2 b1 = ldc(base, 247 + k + d);
        const float2 a0 = ldc(base, 2 + k);
        const float2 b0 = ldc(base, 2 + k + d);
        acc.x += (a1.x * b1.x + a1.y * b1.y) - (a0.x * b0.x + a0.y * b0.y);
        acc.y += (a1.y * b1.x - a1.x * b1.y) - (a0.y * b0.x - a0.x * b0.y);
        *(float2*)(ap + 2 * (offd + k + 1)) = acc;
      }
    }
  }

  // ------- epilogue: one b64 table read per entry + coalesced store ----------
  const float invL = 1.0f / (float)LDIM;
  float* op = out + ((long long)blockIdx.x * BPB + bl) * 128;

#pragma unroll
  for (int q = 0; q < 4; ++q) {
    const int i  = 2 * q + (h >> 3);
    const int j  = h & 7;
    const int d  = (i > j) ? (i - j) : (j - i);
    const int mn = (i < j) ? i : j;
    const int off = (d * (17 - d)) >> 1;

    const float2 r = *(const float2*)(ap + 2 * (off + mn));
    const float xi = (i > j) ? -r.y : r.y;         // Hermitian: R[i][j]=conj(R[j][i])

    const int e = h + 16 * q;                      // e = i*8 + j; coalesced per row
    *(float2*)(op + 2 * e) = make_float2(r.x * invL, xi * invL);
  }
}

extern "C" void kernel_launch(void* const* d_in, const int* in_sizes, int n_in,
                              void* d_out, int out_size, void* d_ws, size_t ws_size,
                              hipStream_t stream) {
  const float* in = (const float*)d_in[0];
  float* out = (float*)d_out;
  hipLaunchKernelGGL(HankelCovLayer_23167053595379_kernel,
                     dim3(NBATCH / BPB), dim3(256), 0, stream, in, out);
}

// Round 4
// 97.241 us; speedup vs baseline: 1.0492x; 1.0050x over previous
//
#include <hip/hip_runtime.h>

// HankelCovLayer: Ry[b,i,j] = (1/L) * sum_l v[i+l] * conj(v[j+l]),
// v[k] = complex(in[b,0,k+2], in[b,1,k+2]), k in [0,252), L=245, i,j in [0,8).
// Row 0 via full dots S[d]; rest via Hankel recurrence prefix table + Hermitian.
// Barrier-free (wave-private LDS dataflow). pk_fma dot formulation:
//   P[d] += (ar,ai)*(br,bi)   -> Sr[d] = P.x + P.y
//   Q[d] += (ai,ar)*(br,bi)   -> Si[d] = Q.x - Q.y   (Si[0] == 0, Q[0] dropped)
// R4: LDS = exactly 32768 B/block -> 5 blocks/CU (was 4). Achieved by
//  (a) padless staging (BSTRIDE 548->512): lane-15 window reads past block 127
//      are clamped (min) -- those slots are only ever b-operands of masked-zero
//      a-terms, so finite garbage is equivalent to the old zero-pad;
//  (b) A-table overlaid into the dead mid-region of the staging buffer
//      (raw dwords [256,328) = logical entries 128..191, dead after window
//      reads; all producer/consumer pairs same-wave, DS in-order).

#define NBATCH   32768
#define SDIM     256
#define LDIM     245
#define BPB      16          // batches per block (4 per wave)
#define BSTRIDE  512         // dwords per batch LDS region (128 16B-blocks)

typedef float v2f __attribute__((ext_vector_type(2)));

__device__ __forceinline__ v2f fma2(v2f a, v2f b, v2f c) {
  return __builtin_elementwise_fma(a, b, c);
}

// XOR-swizzle on 16B-block index: spreads the 8-block lane stride of the
// window reads across banks (<=8 lanes/bank = b128 wave floor).
__device__ __forceinline__ int swz_blk(int blk) {
  return blk ^ ((blk >> 4) & 7);
}

// complex load (entry c) through the swizzled layout; 8B-aligned, in-block
__device__ __forceinline__ float2 ldc(const float* base, int c) {
  const float* p = base + 4 * swz_blk(c >> 1) + 2 * (c & 1);
  return make_float2(p[0], p[1]);
}

// x += dpp_shifted(x); ctrl = row_shr 1,2,4,8 -> 16-lane row sum lands in lane 15
#define DPP_ADD(x, ctrl)                                                            \
  {                                                                                 \
    int _dt = __builtin_amdgcn_update_dpp(0, __builtin_bit_cast(int, (x)),          \
                                          (ctrl), 0xF, 0xF, true);                  \
    (x) += __builtin_bit_cast(float, _dt);                                          \
  }

extern "C" __global__ __launch_bounds__(256, 5)
void HankelCovLayer_23167053595379_kernel(const float* __restrict__ in,
                                          float* __restrict__ out) {
  __shared__ __align__(16) float lds[BPB * BSTRIDE];   // 32768 B exactly

  const int t    = threadIdx.x;
  const int lane = t & 63;
  const int wv   = t >> 6;
  const long long blockBase = (long long)blockIdx.x * BPB * (2 * SDIM);

  // ------- stage: wave wv loads its own 4 batches (interleaved cplx, swizzled)
#pragma unroll
  for (int k = 0; k < 4; ++k) {
    const int bl = wv * 4 + k;
    const float* src = in + blockBase + (long long)bl * (2 * SDIM);
    const float4 re = *(const float4*)(src + 4 * lane);
    const float4 im = *(const float4*)(src + SDIM + 4 * lane);
    float* bb = lds + bl * BSTRIDE;
    *(float4*)(bb + 4 * swz_blk(2 * lane))     = make_float4(re.x, im.x, re.y, im.y);
    *(float4*)(bb + 4 * swz_blk(2 * lane + 1)) = make_float4(re.z, im.z, re.w, im.w);
  }
  // NO __syncthreads: all LDS producer/consumer pairs are within this wave.

  // ------- per-16-lane-group: one batch --------------------------------------
  const int g  = lane >> 4;
  const int h  = lane & 15;
  const int bl = wv * 4 + g;
  const float* base = lds + bl * BSTRIDE;

  // register window: v[16h .. 16h+23]  (logical blocks 8h+1 .. 8h+12, clamped;
  // clamped slots (lane 15, r>=6) are only b-operands of masked-zero a-terms)
  __align__(16) v2f win2[24];
  {
    const int blk0 = 8 * h + 1;
#pragma unroll
    for (int r = 0; r < 12; ++r) {
      const int blk = (blk0 + r < 127) ? (blk0 + r) : 127;
      *(float4*)&win2[2 * r] = *(const float4*)(base + 4 * swz_blk(blk));
    }
  }

  v2f P[8], Q[7];
#pragma unroll
  for (int d = 0; d < 8; ++d) P[d] = (v2f)(0.f);
#pragma unroll
  for (int d = 0; d < 7; ++d) Q[d] = (v2f)(0.f);

  const int l0 = 16 * h;
#pragma unroll
  for (int m = 0; m < 16; ++m) {
    const bool ok = (l0 + m) < LDIM;            // mask tail l >= 245 (lane 15)
    v2f va = win2[m];
    if (!ok) va = (v2f)(0.f);
    const v2f vs = va.yx;                       // (ai, ar)
    P[0] = fma2(va, win2[m], P[0]);             // d=0: b==a (mask via a)
#pragma unroll
    for (int d = 1; d < 8; ++d) {
      const v2f vb = win2[m + d];
      P[d]     = fma2(va, vb, P[d]);            // (ar*br, ai*bi)
      Q[d - 1] = fma2(vs, vb, Q[d - 1]);        // (ai*br, ar*bi)
    }
  }

  float Sr[8], Si[8];
  Sr[0] = P[0].x + P[0].y;
  Si[0] = 0.f;                                  // sum(ai*ar - ar*ai) == 0
#pragma unroll
  for (int d = 1; d < 8; ++d) {
    Sr[d] = P[d].x + P[d].y;
    Si[d] = Q[d - 1].x - Q[d - 1].y;
  }

  // reduce S[d] across the 16-lane row on the VALU (DPP); sums land in lane 15
#pragma unroll
  for (int d = 0; d < 8; ++d) {
    DPP_ADD(Sr[d], 0x111); DPP_ADD(Sr[d], 0x112);
    DPP_ADD(Sr[d], 0x114); DPP_ADD(Sr[d], 0x118);
    if (d) {
      DPP_ADD(Si[d], 0x111); DPP_ADD(Si[d], 0x112);
      DPP_ADD(Si[d], 0x114); DPP_ADD(Si[d], 0x118);
    }
  }

  // ------- prefix table A_d(n) = S[d] + sum_{k<n} delta(d,k), n in [0, 7-d] --
  // triangular layout at offset off(d) = d*(17-d)/2 complex; 36 complex/batch.
  // Overlaid in the staging buffer's dead region: raw dwords [256, 328).
  float* ap = lds + bl * BSTRIDE + 256;
  if (h == 15) {                                   // seed n=0 entries with S[d]
#pragma unroll
    for (int d = 0; d < 8; ++d) {
      const int off = (d * (17 - d)) >> 1;         // compile-time after unroll
      *(float2*)(ap + 2 * off) = make_float2(Sr[d], Si[d]);
    }
  }
  {
    const int d    = h;                            // lanes 0..7 build row d
    const int offd = (h * (17 - h)) >> 1;
    float2 acc = make_float2(0.f, 0.f);
    if (h < 8) acc = *(const float2*)(ap + 2 * offd);   // same-wave LDS RAW
#pragma unroll
    for (int k = 0; k < 7; ++k) {
      if (h + k < 7) {                             // lane d does n = 1..7-d
        const float2 a1 = ldc(base, 247 + k);
        const float2 b1 = ldc(base, 247 + k + d);
        const float2 a0 = ldc(base, 2 + k);
        const float2 b0 = ldc(base, 2 + k + d);
        acc.x += (a1.x * b1.x + a1.y * b1.y) - (a0.x * b0.x + a0.y * b0.y);
        acc.y += (a1.y * b1.x - a1.x * b1.y) - (a0.y * b0.x - a0.x * b0.y);
        *(float2*)(ap + 2 * (offd + k + 1)) = acc;
      }
    }
  }

  // ------- epilogue: one b64 table read per entry + coalesced store ----------
  const float invL = 1.0f / (float)LDIM;
  float* op = out + ((long long)blockIdx.x * BPB + bl) * 128;

#pragma unroll
  for (int q = 0; q < 4; ++q) {
    const int i  = 2 * q + (h >> 3);
    const int j  = h & 7;
    const int d  = (i > j) ? (i - j) : (j - i);
    const int mn = (i < j) ? i : j;
    const int off = (d * (17 - d)) >> 1;

    const float2 r = *(const float2*)(ap + 2 * (off + mn));
    const float xi = (i > j) ? -r.y : r.y;         // Hermitian: R[i][j]=conj(R[j][i])

    const int e = h + 16 * q;                      // e = i*8 + j; coalesced per row
    *(float2*)(op + 2 * e) = make_float2(r.x * invL, xi * invL);
  }
}

extern "C" void kernel_launch(void* const* d_in, const int* in_sizes, int n_in,
                              void* d_out, int out_size, void* d_ws, size_t ws_size,
                              hipStream_t stream) {
  const float* in = (const float*)d_in[0];
  float* out = (float*)d_out;
  hipLaunchKernelGGL(HankelCovLayer_23167053595379_kernel,
                     dim3(NBATCH / BPB), dim3(256), 0, stream, in, out);
}